// Round 1
// baseline (162.848 us; speedup 1.0000x reference)
//
#include <hip/hip_runtime.h>
#include <math.h>

#define E_DIM 256
#define S_DIM 2048
#define B_DIM 8

// ---------------------------------------------------------------------------
// GEMM: C_b = A(256x256) * B_b(256x2048)  (+bias, *scale)
// A row-major [m][k]; B_b row-major [k][n]; out either [m][n] or transposed [n][m].
// 128x128 tile, BK=16, 256 threads, 8x8 microtile.
// n microtile split: n(v) = n0 + tx*4 + (v&3) + (v>>2)*64  (keeps LDS reads 2-way)
// ---------------------------------------------------------------------------
template <bool TRANS_OUT>
__global__ __launch_bounds__(256) void gemm_kernel(
    const float* __restrict__ A, const float* __restrict__ Bm,
    const float* __restrict__ bias, float* __restrict__ C, float scale) {
  const int tid = threadIdx.x;
  const int tx = tid & 15;   // n-dir
  const int ty = tid >> 4;   // m-dir
  const int n0 = blockIdx.x * 128;
  const int m0 = blockIdx.y * 128;
  const int b = blockIdx.z;

  const float* __restrict__ Bb = Bm + (size_t)b * E_DIM * S_DIM;

  // As[k][m] stride 132 (pad: stage-write 2-way, reads broadcast)
  __shared__ __align__(16) float As[16 * 132];
  __shared__ __align__(16) float Bs[16 * 128];

  float acc[8][8];
#pragma unroll
  for (int u = 0; u < 8; ++u)
#pragma unroll
    for (int v = 0; v < 8; ++v) acc[u][v] = 0.f;

  const int aj = tid & 15;   // k within tile (A stage)
  const int ai0 = tid >> 4;  // m base (A stage)
  const int bi = tid & 127;  // n (B stage)
  const int bj0 = tid >> 7;  // k base (B stage)

  for (int k0 = 0; k0 < E_DIM; k0 += 16) {
    __syncthreads();  // protect LDS from previous iteration's readers
#pragma unroll
    for (int r = 0; r < 8; ++r) {
      int i = ai0 + 16 * r;
      As[aj * 132 + i] = A[(size_t)(m0 + i) * E_DIM + k0 + aj];
    }
#pragma unroll
    for (int r = 0; r < 8; ++r) {
      int j = bj0 + 2 * r;
      Bs[j * 128 + bi] = Bb[(size_t)(k0 + j) * S_DIM + n0 + bi];
    }
    __syncthreads();
#pragma unroll
    for (int kk = 0; kk < 16; ++kk) {
      const float4 a0 = *(const float4*)&As[kk * 132 + ty * 8];
      const float4 a1 = *(const float4*)&As[kk * 132 + ty * 8 + 4];
      const float4 b0 = *(const float4*)&Bs[kk * 128 + tx * 4];
      const float4 b1 = *(const float4*)&Bs[kk * 128 + 64 + tx * 4];
      float am[8] = {a0.x, a0.y, a0.z, a0.w, a1.x, a1.y, a1.z, a1.w};
      float bn[8] = {b0.x, b0.y, b0.z, b0.w, b1.x, b1.y, b1.z, b1.w};
#pragma unroll
      for (int u = 0; u < 8; ++u)
#pragma unroll
        for (int v = 0; v < 8; ++v) acc[u][v] += am[u] * bn[v];
    }
  }

  float bi8[8];
#pragma unroll
  for (int u = 0; u < 8; ++u) bi8[u] = bias[m0 + ty * 8 + u];

  if (TRANS_OUT) {
    // C[b][n][m]  (q layout: [t][f], f contiguous)
#pragma unroll
    for (int v = 0; v < 8; ++v) {
      int n = n0 + tx * 4 + (v & 3) + (v >> 2) * 64;
      size_t base = ((size_t)b * S_DIM + n) * E_DIM + m0 + ty * 8;
      float4 w0 = make_float4((acc[0][v] + bi8[0]) * scale, (acc[1][v] + bi8[1]) * scale,
                              (acc[2][v] + bi8[2]) * scale, (acc[3][v] + bi8[3]) * scale);
      float4 w1 = make_float4((acc[4][v] + bi8[4]) * scale, (acc[5][v] + bi8[5]) * scale,
                              (acc[6][v] + bi8[6]) * scale, (acc[7][v] + bi8[7]) * scale);
      *(float4*)&C[base] = w0;
      *(float4*)&C[base + 4] = w1;
    }
  } else {
    // C[b][m][n]
#pragma unroll
    for (int u = 0; u < 8; ++u) {
      int m = m0 + ty * 8 + u;
      size_t base = ((size_t)b * E_DIM + m) * S_DIM + n0 + tx * 4;
      float4 w0 = make_float4((acc[u][0] + bi8[u]) * scale, (acc[u][1] + bi8[u]) * scale,
                              (acc[u][2] + bi8[u]) * scale, (acc[u][3] + bi8[u]) * scale);
      float4 w1 = make_float4((acc[u][4] + bi8[u]) * scale, (acc[u][5] + bi8[u]) * scale,
                              (acc[u][6] + bi8[u]) * scale, (acc[u][7] + bi8[u]) * scale);
      *(float4*)&C[base] = w0;
      *(float4*)&C[base + 64] = w1;
    }
  }
}

// ---------------------------------------------------------------------------
// K2: banded self-attention pooling.
// One block = (b, 32-s tile). energy[s][l] = q[s].q[s+l-4]/24 (pad rows = bq),
// softmax over l=0..8, pooled[b,e,s] = sum_l w[s][l] * x[b,e,s+l-4] (zero pad).
// ---------------------------------------------------------------------------
#define TS 32
#define QROWS 40   // TS + 8
#define QSTR 259   // row stride: (s-strided banded reads become ~2-way = free)

__global__ __launch_bounds__(256) void attn_pool_kernel(
    const float* __restrict__ x, const float* __restrict__ q,
    const float* __restrict__ bq, float* __restrict__ pooled) {
  const int tid = threadIdx.x;
  const int s0 = blockIdx.x * TS;
  const int b = blockIdx.y;

  __shared__ float lds_q[QROWS * QSTR];  // 41440 B
  __shared__ float part2[4 * TS * 9];    // 4608 B
  __shared__ float lds_w[TS * 9];        // 1152 B

  // ---- Phase A: stage q rows t = s0-4 .. s0+TS+3 (OOB rows = bq) ----
  {
    const int r0 = tid >> 6;  // wave id 0..3
    const int fl = tid & 63;
    for (int r = r0; r < QROWS; r += 4) {
      int t = s0 - 4 + r;
      const float* __restrict__ src =
          (t >= 0 && t < S_DIM) ? &q[((size_t)b * S_DIM + t) * E_DIM] : bq;
#pragma unroll
      for (int u = 0; u < 4; ++u) {
        int f = fl + 64 * u;
        lds_q[r * QSTR + f] = src[f];
      }
    }
  }
  __syncthreads();

  // ---- Phase B: banded energies, 12-row sliding register window ----
  const int a = tid & 7;    // s-group: s = s0 + 4a + si
  const int fp = tid >> 3;  // 0..31 f-part; this thread's f = fp + 32*j
  float acc[4][9];
#pragma unroll
  for (int si = 0; si < 4; ++si)
#pragma unroll
    for (int l = 0; l < 9; ++l) acc[si][l] = 0.f;

  for (int j = 0; j < 8; ++j) {
    int f = fp + 32 * j;
    float r[12];
#pragma unroll
    for (int i = 0; i < 12; ++i) r[i] = lds_q[(4 * a + i) * QSTR + f];
#pragma unroll
    for (int si = 0; si < 4; ++si) {
      float c = r[si + 4];  // center row = s
#pragma unroll
      for (int l = 0; l < 9; ++l) acc[si][l] += c * r[si + l];
    }
  }
  // reduce over fp within wave (fp-low lives in lane bits 3..5)
#pragma unroll
  for (int off = 8; off < 64; off <<= 1) {
#pragma unroll
    for (int si = 0; si < 4; ++si)
#pragma unroll
      for (int l = 0; l < 9; ++l) acc[si][l] += __shfl_xor(acc[si][l], off, 64);
  }
  const int wave = tid >> 6;
  if ((tid & 63) < 8) {
#pragma unroll
    for (int si = 0; si < 4; ++si)
#pragma unroll
      for (int l = 0; l < 9; ++l)
        part2[(wave * TS + (4 * a + si)) * 9 + l] = acc[si][l];
  }
  __syncthreads();

  // ---- Phase B2: softmax (threads 0..TS-1) ----
  if (tid < TS) {
    float e[9];
#pragma unroll
    for (int l = 0; l < 9; ++l)
      e[l] = (part2[(0 * TS + tid) * 9 + l] + part2[(1 * TS + tid) * 9 + l] +
              part2[(2 * TS + tid) * 9 + l] + part2[(3 * TS + tid) * 9 + l]) *
             (1.0f / 24.0f);
    float m = e[0];
#pragma unroll
    for (int l = 1; l < 9; ++l) m = fmaxf(m, e[l]);
    float s = 0.f;
#pragma unroll
    for (int l = 0; l < 9; ++l) {
      e[l] = __expf(e[l] - m);
      s += e[l];
    }
    float inv = 1.0f / s;
#pragma unroll
    for (int l = 0; l < 9; ++l) lds_w[tid * 9 + l] = e[l] * inv;
  }
  __syncthreads();

  // ---- Phase C: pooled[b][e][s] = sum_l w[s][l] * x[b][e][s+l-4] ----
  const int sg = tid & 7;   // 4 consecutive s per thread
  const int e0 = tid >> 3;  // 0..31
  float w4[4][9];
#pragma unroll
  for (int si = 0; si < 4; ++si)
#pragma unroll
    for (int l = 0; l < 9; ++l) w4[si][l] = lds_w[(4 * sg + si) * 9 + l];

  const float* __restrict__ xb = x + (size_t)b * E_DIM * S_DIM;
  float* __restrict__ pb = pooled + (size_t)b * E_DIM * S_DIM;
  for (int e = e0; e < E_DIM; e += 32) {
    const float* __restrict__ xr = xb + (size_t)e * S_DIM;
    float r[12];
#pragma unroll
    for (int j = 0; j < 3; ++j) {
      int t = s0 + 4 * sg - 4 + 4 * j;  // 4-aligned chunk: fully in or fully out
      float4 v = (t >= 0 && t < S_DIM) ? *(const float4*)&xr[t]
                                       : make_float4(0.f, 0.f, 0.f, 0.f);
      r[4 * j + 0] = v.x;
      r[4 * j + 1] = v.y;
      r[4 * j + 2] = v.z;
      r[4 * j + 3] = v.w;
    }
    float o[4];
#pragma unroll
    for (int si = 0; si < 4; ++si) {
      float s = 0.f;
#pragma unroll
      for (int l = 0; l < 9; ++l) s += w4[si][l] * r[si + l];
      o[si] = s;
    }
    *(float4*)&pb[(size_t)e * S_DIM + s0 + 4 * sg] = make_float4(o[0], o[1], o[2], o[3]);
  }
}

// ---------------------------------------------------------------------------
extern "C" void kernel_launch(void* const* d_in, const int* in_sizes, int n_in,
                              void* d_out, int out_size, void* d_ws, size_t ws_size,
                              hipStream_t stream) {
  const float* x = (const float*)d_in[0];
  const float* Wq = (const float*)d_in[1];
  const float* bq = (const float*)d_in[2];
  const float* Wo = (const float*)d_in[3];
  const float* bo = (const float*)d_in[4];
  float* out = (float*)d_out;

  float* qws = (float*)d_ws;  // [B][S][E]  16 MB
  float* pooled = qws + (size_t)B_DIM * S_DIM * E_DIM;  // [B][E][S]  16 MB

  // K1: q[b][t][f] = Wq @ x[b] + bq   (transposed epilogue)
  gemm_kernel<true><<<dim3(S_DIM / 128, E_DIM / 128, B_DIM), 256, 0, stream>>>(
      Wq, x, bq, qws, 1.0f);
  // K2: banded attention pooling -> pooled[b][e][s]
  attn_pool_kernel<<<dim3(S_DIM / TS, B_DIM), 256, 0, stream>>>(x, qws, bq, pooled);
  // K3: out[b][f][s] = (Wo @ pooled[b] + bo) / 9
  gemm_kernel<false><<<dim3(S_DIM / 128, E_DIM / 128, B_DIM), 256, 0, stream>>>(
      Wo, pooled, bo, out, 1.0f / 9.0f);
}

// Round 2
// 125.121 us; speedup vs baseline: 1.3015x; 1.3015x over previous
//
#include <hip/hip_runtime.h>
#include <math.h>

#define E_DIM 256
#define S_DIM 2048
#define B_DIM 8

typedef unsigned short u16;
typedef __bf16 bf16x8 __attribute__((ext_vector_type(8)));
typedef float f32x4 __attribute__((ext_vector_type(4)));
typedef u16 u16x8 __attribute__((ext_vector_type(8)));

__device__ inline u16 f2bf(float f) {
  unsigned u = __builtin_bit_cast(unsigned, f);
  unsigned r = (u + 0x7FFF + ((u >> 16) & 1)) >> 16;  // RTNE, finite inputs
  return (u16)r;
}

// ---------------------------------------------------------------------------
// Prep 1: Wq, Wo (fp32 [f][e]) -> bf16 [f][e]
// ---------------------------------------------------------------------------
__global__ __launch_bounds__(256) void convert_w(
    const float* __restrict__ Wq, const float* __restrict__ Wo,
    u16* __restrict__ Wqb, u16* __restrict__ Wob) {
  int idx = (blockIdx.x * 256 + threadIdx.x) * 4;  // grid 128 -> 131072 elems
  const float* src;
  u16* dst;
  if (idx < 65536) { src = Wq + idx; dst = Wqb + idx; }
  else { src = Wo + (idx - 65536); dst = Wob + (idx - 65536); }
  float4 v = *(const float4*)src;
  ushort4 o = make_ushort4(f2bf(v.x), f2bf(v.y), f2bf(v.z), f2bf(v.w));
  *(ushort4*)dst = o;
}

// ---------------------------------------------------------------------------
// Prep 2: x fp32 [b][e][s] -> xT bf16 [b][s][e]  (64x64 LDS-tiled transpose)
// ---------------------------------------------------------------------------
__global__ __launch_bounds__(256) void transpose_x(const float* __restrict__ x,
                                                   u16* __restrict__ xT) {
  __shared__ float t[64 * 68];  // [s_local][e_local], stride 68 (16B-aligned rows)
  const int tid = threadIdx.x;
  const int s0 = blockIdx.x * 64, e0 = blockIdx.y * 64, b = blockIdx.z;
  const int sc = (tid & 15) * 4, ei = tid >> 4;
#pragma unroll
  for (int p = 0; p < 4; ++p) {
    int e = e0 + p * 16 + ei;
    float4 v = *(const float4*)&x[((size_t)b * E_DIM + e) * S_DIM + s0 + sc];
    int ee = p * 16 + ei;
    t[(sc + 0) * 68 + ee] = v.x;
    t[(sc + 1) * 68 + ee] = v.y;
    t[(sc + 2) * 68 + ee] = v.z;
    t[(sc + 3) * 68 + ee] = v.w;
  }
  __syncthreads();
#pragma unroll
  for (int c = tid; c < 512; c += 256) {  // 64 rows x 8 chunks of 8 elems
    int r = c >> 3, h = c & 7;
    const float* p = &t[r * 68 + h * 8];
    u16x8 o;
#pragma unroll
    for (int u = 0; u < 8; ++u) o[u] = f2bf(p[u]);
    *(u16x8*)&xT[((size_t)b * S_DIM + s0 + r) * E_DIM + e0 + h * 8] = o;
  }
}

// ---------------------------------------------------------------------------
// MFMA GEMM: D[b][m=0..2047][n=0..255] = A[b] (M x K, k-contig) . Bw^T (N x K, k-contig)
// 128x128 tile, BK=32, 4 waves (2x2), 4x4 16x16x32 frags per wave.
// LDS rows padded to 40 bf16 (80 B): frag b128 reads 2-way (free).
// EPI 0: q[b][m][n] = acc + bias[n]            (scalar stores, 16-lane coalesced)
// EPI 1: out[b][n][m] = (acc + bias[n])*scale  (float4 along m)
// ---------------------------------------------------------------------------
template <int EPI>
__global__ __launch_bounds__(256) void mfma_gemm(
    const u16* __restrict__ A, const u16* __restrict__ Bw,
    const float* __restrict__ bias, float* __restrict__ C, float scale) {
  __shared__ u16 As[128 * 40];
  __shared__ u16 Bs[128 * 40];
  const int tid = threadIdx.x;
  const int m0 = blockIdx.x * 128, n0 = blockIdx.y * 128, b = blockIdx.z;
  const int wave = tid >> 6, lane = tid & 63;
  const int wm = wave & 1, wn = wave >> 1;
  const int lm = lane & 15, lk = lane >> 4;
  const u16* __restrict__ Ab = A + (size_t)b * S_DIM * E_DIM;

  const f32x4 zero = {0.f, 0.f, 0.f, 0.f};
  f32x4 acc[4][4];
#pragma unroll
  for (int i = 0; i < 4; ++i)
#pragma unroll
    for (int j = 0; j < 4; ++j) acc[i][j] = zero;

  for (int k0 = 0; k0 < E_DIM; k0 += 32) {
    __syncthreads();
#pragma unroll
    for (int c = tid; c < 512; c += 256) {  // A tile: 128 rows x 4 16B-chunks
      int r = c >> 2, off = c & 3;
      *(float4*)&As[r * 40 + off * 8] =
          *(const float4*)&Ab[(size_t)(m0 + r) * E_DIM + k0 + off * 8];
    }
#pragma unroll
    for (int c = tid; c < 512; c += 256) {  // B tile
      int r = c >> 2, off = c & 3;
      *(float4*)&Bs[r * 40 + off * 8] =
          *(const float4*)&Bw[(size_t)(n0 + r) * E_DIM + k0 + off * 8];
    }
    __syncthreads();
    bf16x8 af[4], bfr[4];
#pragma unroll
    for (int i = 0; i < 4; ++i)
      af[i] = *(const bf16x8*)&As[(wm * 64 + i * 16 + lm) * 40 + lk * 8];
#pragma unroll
    for (int j = 0; j < 4; ++j)
      bfr[j] = *(const bf16x8*)&Bs[(wn * 64 + j * 16 + lm) * 40 + lk * 8];
#pragma unroll
    for (int i = 0; i < 4; ++i)
#pragma unroll
      for (int j = 0; j < 4; ++j)
        acc[i][j] = __builtin_amdgcn_mfma_f32_16x16x32_bf16(af[i], bfr[j], acc[i][j], 0, 0, 0);
  }

  if (EPI == 0) {
    // q[b][m][n] (m=s, n=f contiguous)
#pragma unroll
    for (int j = 0; j < 4; ++j) {
      int n = n0 + wn * 64 + j * 16 + lm;
      float bv = bias[n];
#pragma unroll
      for (int i = 0; i < 4; ++i) {
        int m = m0 + wm * 64 + i * 16 + lk * 4;
        size_t base = ((size_t)b * S_DIM + m) * E_DIM + n;
#pragma unroll
        for (int r = 0; r < 4; ++r) C[base + (size_t)r * E_DIM] = acc[i][j][r] + bv;
      }
    }
  } else {
    // out[b][f=n][s=m]: lane holds 4 consecutive m at fixed n -> float4 along s
#pragma unroll
    for (int j = 0; j < 4; ++j) {
      int f = n0 + wn * 64 + j * 16 + lm;
      float bv = bias[f];
#pragma unroll
      for (int i = 0; i < 4; ++i) {
        int s = m0 + wm * 64 + i * 16 + lk * 4;
        float4 v = make_float4((acc[i][j][0] + bv) * scale, (acc[i][j][1] + bv) * scale,
                               (acc[i][j][2] + bv) * scale, (acc[i][j][3] + bv) * scale);
        *(float4*)&C[((size_t)b * E_DIM + f) * S_DIM + s] = v;
      }
    }
  }
}

// ---------------------------------------------------------------------------
// K2: banded attention pooling. energy[s][l] = q[s].q[s+l-4]/24 (pad rows = bq),
// softmax over l, pooledT[b][s][e] (bf16) = sum_l w[s][l] * x[b][e][s+l-4].
// ---------------------------------------------------------------------------
#define TS 32
#define QROWS 40
#define QSTR 259  // phase-B banded reads 2-way (free)
#define OSTR 264

__global__ __launch_bounds__(256) void attn_pool(
    const float* __restrict__ x, const float* __restrict__ q,
    const float* __restrict__ bq, u16* __restrict__ pooledT) {
  const int tid = threadIdx.x;
  const int s0 = blockIdx.x * TS;
  const int b = blockIdx.y;

  __shared__ float lds_q[QROWS * QSTR];  // 41440 B
  __shared__ float part2[4 * TS * 9];    // 4608 B
  __shared__ float lds_w[TS * 9];        // 1152 B
  __shared__ u16 outT[TS * OSTR];        // 16896 B   (total ~64 KB)

  // ---- Phase A: thread == f; rows t = s0-4 .. s0+TS+3 (OOB rows = bq) ----
  {
    const float* __restrict__ qb = q + (size_t)b * S_DIM * E_DIM;
    const float bqv = bq[tid];
#pragma unroll 8
    for (int r = 0; r < QROWS; ++r) {
      int t = s0 - 4 + r;
      float v = (t >= 0 && t < S_DIM) ? qb[(size_t)t * E_DIM + tid] : bqv;
      lds_q[r * QSTR + tid] = v;  // consecutive banks across lanes: conflict-free
    }
  }
  __syncthreads();

  // ---- Phase B: banded energies, 12-row sliding register window ----
  const int a = tid & 7;    // s-group: s = s0 + 4a + si
  const int fp = tid >> 3;  // 0..31 f-part
  float acc[4][9];
#pragma unroll
  for (int si = 0; si < 4; ++si)
#pragma unroll
    for (int l = 0; l < 9; ++l) acc[si][l] = 0.f;

  for (int j = 0; j < 8; ++j) {
    int f = fp + 32 * j;
    float r[12];
#pragma unroll
    for (int i = 0; i < 12; ++i) r[i] = lds_q[(4 * a + i) * QSTR + f];
#pragma unroll
    for (int si = 0; si < 4; ++si) {
      float c = r[si + 4];
#pragma unroll
      for (int l = 0; l < 9; ++l) acc[si][l] += c * r[si + l];
    }
  }
#pragma unroll
  for (int off = 8; off < 64; off <<= 1) {
#pragma unroll
    for (int si = 0; si < 4; ++si)
#pragma unroll
      for (int l = 0; l < 9; ++l) acc[si][l] += __shfl_xor(acc[si][l], off, 64);
  }
  const int wave = tid >> 6;
  if ((tid & 63) < 8) {
#pragma unroll
    for (int si = 0; si < 4; ++si)
#pragma unroll
      for (int l = 0; l < 9; ++l)
        part2[(wave * TS + (4 * a + si)) * 9 + l] = acc[si][l];
  }
  __syncthreads();

  // ---- Phase B2: softmax (threads 0..TS-1) ----
  if (tid < TS) {
    float e[9];
#pragma unroll
    for (int l = 0; l < 9; ++l)
      e[l] = (part2[(0 * TS + tid) * 9 + l] + part2[(1 * TS + tid) * 9 + l] +
              part2[(2 * TS + tid) * 9 + l] + part2[(3 * TS + tid) * 9 + l]) *
             (1.0f / 24.0f);
    float m = e[0];
#pragma unroll
    for (int l = 1; l < 9; ++l) m = fmaxf(m, e[l]);
    float s = 0.f;
#pragma unroll
    for (int l = 0; l < 9; ++l) {
      e[l] = __expf(e[l] - m);
      s += e[l];
    }
    float inv = 1.0f / s;
#pragma unroll
    for (int l = 0; l < 9; ++l) lds_w[tid * 9 + l] = e[l] * inv;
  }
  __syncthreads();

  // ---- Phase C: pooled into LDS tile (bf16), then coalesced writeback ----
  const int sg = tid & 7;
  const int e0 = tid >> 3;
  float w4[4][9];
#pragma unroll
  for (int si = 0; si < 4; ++si)
#pragma unroll
    for (int l = 0; l < 9; ++l) w4[si][l] = lds_w[(4 * sg + si) * 9 + l];

  const float* __restrict__ xb = x + (size_t)b * E_DIM * S_DIM;
  for (int e = e0; e < E_DIM; e += 32) {
    const float* __restrict__ xr = xb + (size_t)e * S_DIM;
    float r[12];
#pragma unroll
    for (int j = 0; j < 3; ++j) {
      int t = s0 + 4 * sg - 4 + 4 * j;  // 4-aligned: fully in or fully out
      float4 v = (t >= 0 && t < S_DIM) ? *(const float4*)&xr[t]
                                       : make_float4(0.f, 0.f, 0.f, 0.f);
      r[4 * j + 0] = v.x;
      r[4 * j + 1] = v.y;
      r[4 * j + 2] = v.z;
      r[4 * j + 3] = v.w;
    }
#pragma unroll
    for (int si = 0; si < 4; ++si) {
      float s = 0.f;
#pragma unroll
      for (int l = 0; l < 9; ++l) s += w4[si][l] * r[si + l];
      outT[(4 * sg + si) * OSTR + e] = f2bf(s);
    }
  }
  __syncthreads();
#pragma unroll
  for (int c = tid; c < TS * 32; c += 256) {  // 32 rows x 32 chunks of 8
    int r = c >> 5, h = c & 31;
    u16x8 v = *(const u16x8*)&outT[r * OSTR + h * 8];
    *(u16x8*)&pooledT[((size_t)b * S_DIM + s0 + r) * E_DIM + h * 8] = v;
  }
}

// ---------------------------------------------------------------------------
extern "C" void kernel_launch(void* const* d_in, const int* in_sizes, int n_in,
                              void* d_out, int out_size, void* d_ws, size_t ws_size,
                              hipStream_t stream) {
  const float* x = (const float*)d_in[0];
  const float* Wq = (const float*)d_in[1];
  const float* bq = (const float*)d_in[2];
  const float* Wo = (const float*)d_in[3];
  const float* bo = (const float*)d_in[4];
  float* out = (float*)d_out;

  // ws layout: [0,16M): q fp32 [b][s][f]; [16M,24M): xT bf16 [b][s][e]
  // (aliased by pooledT bf16 [b][s][e] after K1 consumes xT); [24M,+256K): weights
  float* q = (float*)d_ws;
  u16* xT = (u16*)((char*)d_ws + ((size_t)16 << 20));
  u16* pooledT = xT;
  u16* Wqb = (u16*)((char*)d_ws + ((size_t)24 << 20));
  u16* Wob = Wqb + 65536;

  convert_w<<<128, 256, 0, stream>>>(Wq, Wo, Wqb, Wob);
  transpose_x<<<dim3(32, 4, 8), 256, 0, stream>>>(x, xT);
  // K1: q[b][s][f] = xT[b] . Wq^T + bq
  mfma_gemm<0><<<dim3(16, 2, 8), 256, 0, stream>>>(xT, Wqb, bq, q, 1.0f);
  // K2: banded attention pooling -> pooledT bf16 [b][s][e]
  attn_pool<<<dim3(S_DIM / TS, B_DIM), 256, 0, stream>>>(x, q, bq, pooledT);
  // K3: out[b][f][s] = (pooledT[b] . Wo^T + bo) / 9
  mfma_gemm<1><<<dim3(16, 2, 8), 256, 0, stream>>>(pooledT, Wob, bo, out, 1.0f / 9.0f);
}

// Round 3
// 103.841 us; speedup vs baseline: 1.5682x; 1.2049x over previous
//
#include <hip/hip_runtime.h>

#define E_DIM 256
#define S_DIM 2048
#define B_DIM 8

typedef unsigned short u16;
typedef __bf16 bf16x8 __attribute__((ext_vector_type(8)));
typedef float f32x4 __attribute__((ext_vector_type(4)));
typedef u16 u16x8 __attribute__((ext_vector_type(8)));

__device__ inline u16 f2bf(float f) {
  unsigned u = __builtin_bit_cast(unsigned, f);
  return (u16)((u + 0x7FFF + ((u >> 16) & 1)) >> 16);  // RTNE, finite inputs
}
__device__ inline float bf2f(u16 v) {
  unsigned u = ((unsigned)v) << 16;
  return __builtin_bit_cast(float, u);
}

// ---------------------------------------------------------------------------
// Prep: Wq, Wo (fp32 [f][e]) -> bf16 [f][e]
// ---------------------------------------------------------------------------
__global__ __launch_bounds__(256) void convert_w(
    const float* __restrict__ Wq, const float* __restrict__ Wo,
    u16* __restrict__ Wqb, u16* __restrict__ Wob) {
  int idx = (blockIdx.x * 256 + threadIdx.x) * 4;  // grid 128 -> 131072 elems
  const float* src;
  u16* dst;
  if (idx < 65536) { src = Wq + idx; dst = Wqb + idx; }
  else { src = Wo + (idx - 65536); dst = Wob + (idx - 65536); }
  float4 v = *(const float4*)src;
  ushort4 o = make_ushort4(f2bf(v.x), f2bf(v.y), f2bf(v.z), f2bf(v.w));
  *(ushort4*)dst = o;
}

// ---------------------------------------------------------------------------
// Fused kernel: one block = (b, 32-s tile). Phases:
//  P0: register-transpose stage xt[r][e] bf16, r=0..47 (t = s0-4+r; OOB/pad -> 0)
//  P1: q = xt . Wq^T + bq (MFMA, M=48 N=256 K=256) -> qt bf16 [40][266]
//  P2: banded energies from qt, cross-wave reduce, softmax -> ldsw[32][9]
//  P3: pooled[s][e] = sum_l w[s][l] * xt[s+l][e]  (bf16, aliases qt)
//  P4: out[b][f][s] = (pooled . Wo^T + bo)/9 (MFMA, M=32 N=256 K=256)
// Zero-staged OOB rows make q_row = bq exactly (reference padding semantics)
// and give zero-padded pooling for free.
// ---------------------------------------------------------------------------
#define TS 32
#define QR 40      // staged rows: t = s0-4 .. s0+35
#define XROWS 48   // padded to 3 m-frags of 16
#define XSTR 264   // u16 row stride (132 words ≡ 4 mod 32: balanced frag reads)
#define QSTR 266   // u16 (133 words odd: banded scalar reads conflict-free)
#define PSTR 264

__global__ __launch_bounds__(256) void fused_attn(
    const float* __restrict__ x, const u16* __restrict__ Wqb,
    const float* __restrict__ bq, const u16* __restrict__ Wob,
    const float* __restrict__ bo, float* __restrict__ out) {
  // LDS: xt 25344 | qt 21280 (pooled 16896 aliases) | part2 4608 | ldsw 1152
  __shared__ __align__(16) char smem[52384];
  u16* xt = (u16*)smem;
  u16* qt = (u16*)(smem + 25344);
  u16* pooled = qt;
  float* part2 = (float*)(smem + 46624);  // [4][TS][9]
  float* ldsw = (float*)(smem + 51232);   // [TS][9]

  const int tid = threadIdx.x;
  const int s0 = blockIdx.x * TS;
  const int b = blockIdx.y;
  const int wave = tid >> 6, lane = tid & 63;
  const int lm = lane & 15, lk = lane >> 4;

  // ---- P0: stage xt (lane = row, e-contig accumulated in registers) ----
  {
    const int r = lane;      // row 0..63, valid < 48
    const int g = wave;      // e-quarter
    const int t = s0 - 4 + r;
    const bool v = (r < QR) && (t >= 0) && (t < S_DIM);
    if (r < XROWS) {
      const float* __restrict__ xb = x + (size_t)b * E_DIM * S_DIM + t;
#pragma unroll
      for (int eb = 0; eb < 64; eb += 8) {
        u16x8 v8;
#pragma unroll
        for (int u = 0; u < 8; ++u) {
          int e = g * 64 + eb + u;
          float xv = v ? xb[(size_t)e * S_DIM] : 0.f;  // coalesced across lanes
          v8[u] = f2bf(xv);
        }
        *(u16x8*)&xt[r * XSTR + g * 64 + eb] = v8;  // conflict-free b128
      }
    }
  }
  __syncthreads();

  // ---- P1: K1 MFMA -> qt ----
  {
    const f32x4 zero = {0.f, 0.f, 0.f, 0.f};
    f32x4 acc[3][4];
#pragma unroll
    for (int i = 0; i < 3; ++i)
#pragma unroll
      for (int j = 0; j < 4; ++j) acc[i][j] = zero;
#pragma unroll
    for (int k0 = 0; k0 < 8; ++k0) {
      bf16x8 af[3], bf[4];
#pragma unroll
      for (int i = 0; i < 3; ++i)
        af[i] = *(const bf16x8*)&xt[(i * 16 + lm) * XSTR + k0 * 32 + lk * 8];
#pragma unroll
      for (int j = 0; j < 4; ++j)
        bf[j] = *(const bf16x8*)&Wqb[(size_t)(wave * 64 + j * 16 + lm) * E_DIM +
                                     k0 * 32 + lk * 8];
#pragma unroll
      for (int i = 0; i < 3; ++i)
#pragma unroll
        for (int j = 0; j < 4; ++j)
          acc[i][j] = __builtin_amdgcn_mfma_f32_16x16x32_bf16(af[i], bf[j], acc[i][j], 0, 0, 0);
    }
#pragma unroll
    for (int j = 0; j < 4; ++j) {
      int f = wave * 64 + j * 16 + lm;
      float bv = bq[f];
#pragma unroll
      for (int i = 0; i < 3; ++i) {
        int row = i * 16 + lk * 4;
#pragma unroll
        for (int r2 = 0; r2 < 4; ++r2)
          if (row + r2 < QR) qt[(row + r2) * QSTR + f] = f2bf(acc[i][j][r2] + bv);
      }
    }
  }
  __syncthreads();

  // ---- P2: banded energies + softmax ----
  {
    const int a = tid & 7;     // s-group: s = 4a+si
    const int fpg = tid >> 3;  // 0..31
    float accE[4][9];
#pragma unroll
    for (int si = 0; si < 4; ++si)
#pragma unroll
      for (int l = 0; l < 9; ++l) accE[si][l] = 0.f;
    for (int j = 0; j < 8; ++j) {
      int f = fpg + 32 * j;
      float rr[12];
#pragma unroll
      for (int i = 0; i < 12; ++i) rr[i] = bf2f(qt[(4 * a + i) * QSTR + f]);
#pragma unroll
      for (int si = 0; si < 4; ++si) {
        float c = rr[si + 4];
#pragma unroll
        for (int l = 0; l < 9; ++l) accE[si][l] += c * rr[si + l];
      }
    }
#pragma unroll
    for (int off = 8; off < 64; off <<= 1)
#pragma unroll
      for (int si = 0; si < 4; ++si)
#pragma unroll
        for (int l = 0; l < 9; ++l) accE[si][l] += __shfl_xor(accE[si][l], off, 64);
    if ((tid & 63) < 8)
#pragma unroll
      for (int si = 0; si < 4; ++si)
#pragma unroll
        for (int l = 0; l < 9; ++l)
          part2[(wave * TS + 4 * a + si) * 9 + l] = accE[si][l];
  }
  __syncthreads();
  if (tid < TS) {
    float e[9];
#pragma unroll
    for (int l = 0; l < 9; ++l)
      e[l] = (part2[(0 * TS + tid) * 9 + l] + part2[(1 * TS + tid) * 9 + l] +
              part2[(2 * TS + tid) * 9 + l] + part2[(3 * TS + tid) * 9 + l]) *
             (1.0f / 24.0f);
    float m = e[0];
#pragma unroll
    for (int l = 1; l < 9; ++l) m = fmaxf(m, e[l]);
    float s = 0.f;
#pragma unroll
    for (int l = 0; l < 9; ++l) {
      e[l] = __expf(e[l] - m);
      s += e[l];
    }
    float inv = 1.0f / s;
#pragma unroll
    for (int l = 0; l < 9; ++l) ldsw[tid * 9 + l] = e[l] * inv;
  }
  __syncthreads();

  // ---- P3: pooled[s][e] = sum_l w[s][l] * xt[s+l][e]  (overlays qt) ----
  {
    const int s = tid & 31, ep = tid >> 5;
    float w9[9];
#pragma unroll
    for (int l = 0; l < 9; ++l) w9[l] = ldsw[s * 9 + l];
#pragma unroll
    for (int c = 0; c < 4; ++c) {
      int e8 = ep * 32 + c * 8;
      float o[8];
#pragma unroll
      for (int u = 0; u < 8; ++u) o[u] = 0.f;
#pragma unroll
      for (int l = 0; l < 9; ++l) {
        u16x8 xv = *(const u16x8*)&xt[(s + l) * XSTR + e8];
#pragma unroll
        for (int u = 0; u < 8; ++u) o[u] += w9[l] * bf2f(xv[u]);
      }
      u16x8 pv;
#pragma unroll
      for (int u = 0; u < 8; ++u) pv[u] = f2bf(o[u]);
      *(u16x8*)&pooled[s * PSTR + e8] = pv;
    }
  }
  __syncthreads();

  // ---- P4: K3 MFMA -> out[b][f][s] ----
  {
    const f32x4 zero = {0.f, 0.f, 0.f, 0.f};
    f32x4 acc[2][4];
#pragma unroll
    for (int i = 0; i < 2; ++i)
#pragma unroll
      for (int j = 0; j < 4; ++j) acc[i][j] = zero;
#pragma unroll
    for (int k0 = 0; k0 < 8; ++k0) {
      bf16x8 af[2], bf[4];
#pragma unroll
      for (int i = 0; i < 2; ++i)
        af[i] = *(const bf16x8*)&pooled[(i * 16 + lm) * PSTR + k0 * 32 + lk * 8];
#pragma unroll
      for (int j = 0; j < 4; ++j)
        bf[j] = *(const bf16x8*)&Wob[(size_t)(wave * 64 + j * 16 + lm) * E_DIM +
                                     k0 * 32 + lk * 8];
#pragma unroll
      for (int i = 0; i < 2; ++i)
#pragma unroll
        for (int j = 0; j < 4; ++j)
          acc[i][j] = __builtin_amdgcn_mfma_f32_16x16x32_bf16(af[i], bf[j], acc[i][j], 0, 0, 0);
    }
#pragma unroll
    for (int j = 0; j < 4; ++j) {
      int f = wave * 64 + j * 16 + lm;
      float bv = bo[f];
#pragma unroll
      for (int i = 0; i < 2; ++i) {
        int sl = i * 16 + lk * 4;
        float4 w = make_float4((acc[i][j][0] + bv) * (1.0f / 9.0f),
                               (acc[i][j][1] + bv) * (1.0f / 9.0f),
                               (acc[i][j][2] + bv) * (1.0f / 9.0f),
                               (acc[i][j][3] + bv) * (1.0f / 9.0f));
        *(float4*)&out[((size_t)b * E_DIM + f) * S_DIM + s0 + sl] = w;
      }
    }
  }
}

// ---------------------------------------------------------------------------
extern "C" void kernel_launch(void* const* d_in, const int* in_sizes, int n_in,
                              void* d_out, int out_size, void* d_ws, size_t ws_size,
                              hipStream_t stream) {
  const float* x = (const float*)d_in[0];
  const float* Wq = (const float*)d_in[1];
  const float* bq = (const float*)d_in[2];
  const float* Wo = (const float*)d_in[3];
  const float* bo = (const float*)d_in[4];
  float* out = (float*)d_out;

  u16* Wqb = (u16*)d_ws;
  u16* Wob = Wqb + 65536;

  convert_w<<<128, 256, 0, stream>>>(Wq, Wo, Wqb, Wob);
  fused_attn<<<dim3(S_DIM / TS, B_DIM), 256, 0, stream>>>(x, Wqb, bq, Wob, bo, out);
}